// Round 13
// baseline (17722.035 us; speedup 1.0000x reference)
//
#include <hip/hip_runtime.h>
#include <math.h>

#define Bsz 512
#define Tsz 1024
#define Vsz 27
#define Hsz 512
#define BH (Bsz * Hsz)
#define TV (Tsz * Vsz)
#define NBLK 256
#define NT 512
#define JB 32        // blocks per group (= per chain-pair)
#define NG 48        // gate rows per block (16 r + 16 z + 16 n)

typedef float f32x4 __attribute__((ext_vector_type(4)));
typedef short s16x8 __attribute__((ext_vector_type(8)));
typedef unsigned int u32x4 __attribute__((ext_vector_type(4)));
#define MFMA __builtin_amdgcn_mfma_f32_16x16x32_bf16

// ws byte offsets
#define WS_CNT  ((size_t)2 * 3 * BH * 2)              // counters region (4KB)
#define WS_DSTG (WS_CNT + 4096)                       // 32KB decode stream
#define WS_WXG  (WS_DSTG + (size_t)2 * 16 * 512 * 2)  // 192KB x-fold W stream

__device__ __forceinline__ unsigned short btrunc(float x) {
    return (unsigned short)(__float_as_uint(x) >> 16);
}
__device__ __forceinline__ float bup(unsigned short b) {
    return __uint_as_float(((unsigned)b) << 16);
}
__device__ __forceinline__ unsigned short brne(float x) {
    unsigned u = __float_as_uint(x);
    return (unsigned short)((u + 0x7FFFu + ((u >> 16) & 1u)) >> 16);
}
__device__ __forceinline__ __amdgpu_buffer_rsrc_t make_rsrc(void* p, unsigned bytes) {
    return __builtin_amdgcn_make_buffer_rsrc(p, (short)0, (int)bytes, 0x00020000);
}
template<bool FAST>
__device__ __forceinline__ s16x8 loadA(__amdgpu_buffer_rsrc_t r, int off) {
    u32x4 d = __builtin_amdgcn_raw_buffer_load_b128(r, off, 0, FAST ? 0 : 0x11);
    return __builtin_bit_cast(s16x8, d);
}
template<bool FAST>
__device__ __forceinline__ void storeH(__amdgpu_buffer_rsrc_t r, int off, unsigned short v) {
    __builtin_amdgcn_raw_buffer_store_b16(v, r, off, 0, FAST ? 0 : 0x11);
}

#define PROD6(ACC, B1_, B2_, B3_, A1_, A2_, A3_) do { \
    ACC = MFMA(A1_, B1_, ACC, 0, 0, 0); \
    ACC = MFMA(A1_, B2_, ACC, 0, 0, 0); \
    ACC = MFMA(A2_, B1_, ACC, 0, 0, 0); \
    ACC = MFMA(A1_, B3_, ACC, 0, 0, 0); \
    ACC = MFMA(A2_, B2_, ACC, 0, 0, 0); \
    ACC = MFMA(A3_, B1_, ACC, 0, 0, 0); } while (0)
#define PROD5(ACC, B1_, B2_, A1_, A2_, A3_) do { \
    ACC = MFMA(A1_, B1_, ACC, 0, 0, 0); \
    ACC = MFMA(A1_, B2_, ACC, 0, 0, 0); \
    ACC = MFMA(A2_, B1_, ACC, 0, 0, 0); \
    ACC = MFMA(A2_, B2_, ACC, 0, 0, 0); \
    ACC = MFMA(A3_, B1_, ACC, 0, 0, 0); } while (0)

__global__ void init_ws_kernel(unsigned short* __restrict__ hpl, unsigned* __restrict__ cntr,
                               unsigned short* __restrict__ Dstg, unsigned short* __restrict__ Wxg,
                               const float* __restrict__ W_ih, const float* __restrict__ W_dec)
{
    size_t gid = (size_t)blockIdx.x * 256 + threadIdx.x;
    size_t gsz = (size_t)gridDim.x * 256;
    for (size_t i = gid; i < (size_t)(2 * 3 * BH * 2) / 16; i += gsz)
        ((uint4*)hpl)[i] = make_uint4(0u, 0u, 0u, 0u);
    if (gid < 1024) cntr[gid] = 0u;
    for (size_t i = gid; i < 2 * 16 * 512; i += gsz) {
        int e = i & 7, ln2 = (i >> 3) & 63, c = (i >> 9) & 15, jj = (int)(i >> 13);
        int cc2 = ln2 & 15, qq2 = ln2 >> 4;
        int k = c * 32 + qq2 * 8 + e;
        int vr = jj * 16 + cc2;
        Dstg[i] = (vr < Vsz) ? brne(W_dec[(size_t)vr * Hsz + k]) : (unsigned short)0;
    }
    for (size_t i = gid; i < 1536 * 64; i += gsz) {
        int k = i & 31, p = (i >> 5) & 1, grow = (int)(i >> 6);
        float v = (k < Vsz) ? W_ih[grow * Vsz + k] : 0.f;
        unsigned short t1 = btrunc(v); float r1 = v - bup(t1);
        unsigned short t2 = btrunc(r1);
        Wxg[i] = p ? t2 : t1;
    }
}

__device__ __forceinline__ void group_barrier(unsigned* c, unsigned target) {
    __syncthreads();
    if (threadIdx.x == 0) {
        __hip_atomic_fetch_add(c, 1u, __ATOMIC_RELAXED, __HIP_MEMORY_SCOPE_AGENT);
        while (__hip_atomic_load(c, __ATOMIC_RELAXED, __HIP_MEMORY_SCOPE_AGENT) < target)
            __builtin_amdgcn_s_sleep(2);
    }
    __syncthreads();
}

// One chain, one timestep. Wave roles: half=w>>2 (0: r,z | 1: n,dec),
// kh=(w>>1)&1 (K-half), m=w&1 (16-row M-tile). kh partials reduced via P0/P1.
template<bool FAST>
__device__ __forceinline__ void segment(
    int i, int b0, int g0, int j, unsigned* cntX, float* xsX, float* hk,
    const float* __restrict__ x, float* __restrict__ out,
    const unsigned short* __restrict__ Dstg, const unsigned short* __restrict__ Wxg,
    const unsigned short* Bst, float* P0, float* P1,
    const float* bihL, const float* bhhL, float bdv,
    __amdgpu_buffer_rsrc_t hrs)
{
    const int tid = threadIdx.x;
    const int w = tid >> 6, ln = tid & 63;
    const int half = w >> 2, kh = (w >> 1) & 1, m = w & 1;
    const int cc = ln & 15, qq = ln >> 4;
    const int rowA = (m << 4) + cc;
    const int slot = ((m << 6) + ln) << 3;     // 8 floats per thread in P
    const int vcol = (j << 4) + cc;

    // S0: wait for h_i of this chain (hidden under the other chain's compute)
    if (tid == 0) {
        while (__hip_atomic_load(cntX, __ATOMIC_RELAXED, __HIP_MEMORY_SCOPE_AGENT)
               < (unsigned)JB * (unsigned)i)
            __builtin_amdgcn_s_sleep(1);
    }
    __syncthreads();
    if (FAST) asm volatile("buffer_inv" ::: "memory");   // drop stale L1 lines

    // x_{i+1} prefetch (2 floats/thread)
    float xr0 = 0.f, xr1 = 0.f;
    const int pxr = tid >> 4, pxc = (tid & 15) << 1;
    if (i + 1 < Tsz) {
        const float* xp = x + (size_t)(b0 + pxr) * TV + (size_t)(i + 1) * Vsz;
        if (pxc < Vsz)     xr0 = xp[pxc];
        if (pxc + 1 < Vsz) xr1 = xp[pxc + 1];
    }

    const int par = (i & 1) * (3 * BH * 2);
    const int voffA0 = par + (((b0 + rowA) * Hsz + (qq << 3)) << 1);
    const int ckb = kh << 3;

    f32x4 acc0 = {0,0,0,0}, acc1 = {0,0,0,0}, accD = {0,0,0,0};
    // half0: acc0=R, acc1=Z ; half1: acc0=Nh, acc1=Ni

    s16x8 A1s[4], A2s[4], A3s[4];
    #pragma unroll
    for (int c0 = 0; c0 < 4; ++c0) {
        int off = voffA0 + (ckb + c0) * 64;
        A1s[c0] = loadA<FAST>(hrs, off);
        A2s[c0] = loadA<FAST>(hrs, off + BH * 2);
        A3s[c0] = loadA<FAST>(hrs, off + 2 * BH * 2);
    }
    #pragma unroll
    for (int c = 0; c < 8; ++c) {
        const int sl = c & 3;
        s16x8 A1 = A1s[sl], A2 = A2s[sl], A3 = A3s[sl];
        const int ck = ckb + c;
        const unsigned short* bs = Bst + (size_t)(ck * 9) * 512 + (ln << 3);
        if (half == 0) {
            s16x8 B1 = *(const s16x8*)(bs);
            s16x8 B2 = *(const s16x8*)(bs + 512);
            s16x8 B3 = *(const s16x8*)(bs + 1024);
            PROD6(acc0, B1, B2, B3, A1, A2, A3);
            s16x8 C1 = *(const s16x8*)(bs + 1536);
            s16x8 C2 = *(const s16x8*)(bs + 2048);
            s16x8 C3 = *(const s16x8*)(bs + 2560);
            PROD6(acc1, C1, C2, C3, A1, A2, A3);
        } else {
            s16x8 N1 = *(const s16x8*)(bs + 3072);
            s16x8 N2 = *(const s16x8*)(bs + 3584);
            s16x8 N3 = *(const s16x8*)(bs + 4096);
            PROD6(acc0, N1, N2, N3, A1, A2, A3);
            if (j < 2) {
                s16x8 D1 = *(const s16x8*)(Dstg + (size_t)((j << 4) + ck) * 512 + (ln << 3));
                accD = MFMA(A1, D1, accD, 0, 0, 0);
                accD = MFMA(A2, D1, accD, 0, 0, 0);
            }
        }
        if (c < 4) {
            int off = voffA0 + (ckb + c + 4) * 64;
            A1s[sl] = loadA<FAST>(hrs, off);
            A2s[sl] = loadA<FAST>(hrs, off + BH * 2);
            A3s[sl] = loadA<FAST>(hrs, off + 2 * BH * 2);
        }
    }

    // x-fold on kh1 waves (triple-split fp32 x; 2-plane W from global stream)
    if (kh == 1 && i < Tsz) {
        s16x8 A1, A2, A3;
        #pragma unroll
        for (int e = 0; e < 8; ++e) {
            int k = (qq << 3) + e;
            float v = (k < 28) ? xsX[rowA * 28 + k] : 0.f;   // col27 = zero pad
            unsigned short s1 = btrunc(v); float r1 = v - bup(s1);
            unsigned short s2 = btrunc(r1); float r2 = r1 - bup(s2);
            unsigned short s3 = btrunc(r2);
            A1[e] = (short)s1; A2[e] = (short)s2; A3[e] = (short)s3;
        }
        if (half == 0) {
            const unsigned short* wb = Wxg + (size_t)(g0 + cc) * 64 + (qq << 3);
            s16x8 B1 = *(const s16x8*)(wb); s16x8 B2 = *(const s16x8*)(wb + 32);
            PROD5(acc0, B1, B2, A1, A2, A3);
            wb = Wxg + (size_t)(Hsz + g0 + cc) * 64 + (qq << 3);
            B1 = *(const s16x8*)(wb); B2 = *(const s16x8*)(wb + 32);
            PROD5(acc1, B1, B2, A1, A2, A3);
        } else {
            const unsigned short* wb = Wxg + (size_t)(2 * Hsz + g0 + cc) * 64 + (qq << 3);
            s16x8 B1 = *(const s16x8*)(wb); s16x8 B2 = *(const s16x8*)(wb + 32);
            PROD5(acc1, B1, B2, A1, A2, A3);    // Ni
        }
    }
    __syncthreads();                            // sync1: K-loop + xfold done
    if (kh == 1) {
        float* P = (half == 0) ? P0 : P1;
        *(f32x4*)&P[slot] = acc0;
        *(f32x4*)&P[slot + 4] = acc1;
    }
    __syncthreads();                            // sync2: partials published
    float nh_t[4], ni_t[4];
    if (kh == 0) {
        if (half == 0) {
            f32x4 pa = *(const f32x4*)&P0[slot];
            f32x4 pb = *(const f32x4*)&P0[slot + 4];
            acc0 += pa; acc1 += pb;             // R, Z totals
        } else {
            f32x4 pa = *(const f32x4*)&P1[slot];
            f32x4 pb = *(const f32x4*)&P1[slot + 4];
            #pragma unroll
            for (int r = 0; r < 4; ++r) { nh_t[r] = acc0[r] + pa[r]; ni_t[r] = pb[r]; }
        }
    }
    __syncthreads();                            // sync3: partials consumed
    if (half == 1 && kh == 0) {
        #pragma unroll
        for (int r = 0; r < 4; ++r) { P0[slot + r] = nh_t[r]; P0[slot + 4 + r] = ni_t[r]; }
    }
    __syncthreads();                            // sync4: nh/ni published
    if (half == 0 && kh == 0 && i < Tsz) {
        const int wpar = ((i + 1) & 1) * (3 * BH * 2);
        #pragma unroll
        for (int r = 0; r < 4; ++r) {
            float rv = acc0[r] + bihL[cc] + bhhL[cc];
            float zv = acc1[r] + bihL[16 + cc] + bhhL[16 + cc];
            float nh = P0[slot + r] + bhhL[32 + cc];
            float ni = P0[slot + 4 + r] + bihL[32 + cc];
            float rg = 1.f / (1.f + expf(-rv));
            float zg = 1.f / (1.f + expf(-zv));
            float ng = tanhf(ni + rg * nh);
            float hv = (1.f - zg) * ng + zg * hk[r];
            hk[r] = hv;
            int e2 = wpar + (((b0 + (m << 4) + (qq << 2) + r) * Hsz + g0 + cc) << 1);
            unsigned short s1 = btrunc(hv); float r1 = hv - bup(s1);
            unsigned short s2 = btrunc(r1); float r2 = r1 - bup(s2);
            unsigned short s3 = btrunc(r2);
            storeH<FAST>(hrs, e2, s1);
            storeH<FAST>(hrs, e2 + BH * 2, s2);
            storeH<FAST>(hrs, e2 + 2 * BH * 2, s3);
        }
    }
    asm volatile("s_waitcnt vmcnt(0)" ::: "memory");   // h stores at coherence pt
    __syncthreads();                            // sync5: all stores drained
    if (i < Tsz && tid == 0)
        __hip_atomic_fetch_add(cntX, 1u, __ATOMIC_RELAXED, __HIP_MEMORY_SCOPE_AGENT);
    // S4 (off critical path): xs for i+1; decode reduce + out
    if (i + 1 < Tsz) {
        if (pxc < 28)     xsX[pxr * 28 + pxc] = xr0;
        if (pxc + 1 < 28) xsX[pxr * 28 + pxc + 1] = xr1;
    }
    if (half == 1 && kh == 1 && j < 2)
        *(f32x4*)&P0[slot] = accD;              // P0 free after sync5
    __syncthreads();                            // sync6
    if (half == 1 && kh == 0 && j < 2 && i > 0 && vcol < Vsz) {
        f32x4 pd = *(const f32x4*)&P0[slot];
        #pragma unroll
        for (int r = 0; r < 4; ++r) {
            size_t brow = (size_t)(b0 + (m << 4) + (qq << 2) + r);
            out[brow * TV + (size_t)(i - 1) * Vsz + vcol] = accD[r] + pd[r] + bdv;
        }
    }
}

template<bool FAST>
__device__ __forceinline__ void run_chains(
    int b0A, int b0B, int g0, int j, unsigned* cntA, unsigned* cntB,
    float* xsA, float* xsB, const float* x, float* out,
    const unsigned short* Dstg, const unsigned short* Wxg,
    const unsigned short* Bst, float* P0, float* P1,
    const float* bihL, const float* bhhL, float bdv, __amdgpu_buffer_rsrc_t hrs)
{
    float hkA[4] = {0.f, 0.f, 0.f, 0.f};
    float hkB[4] = {0.f, 0.f, 0.f, 0.f};
    for (int i = 0; i <= Tsz; ++i) {
        segment<FAST>(i, b0A, g0, j, cntA, xsA, hkA, x, out, Dstg, Wxg, Bst,
                      P0, P1, bihL, bhhL, bdv, hrs);
        segment<FAST>(i, b0B, g0, j, cntB, xsB, hkB, x, out, Dstg, Wxg, Bst,
                      P0, P1, bihL, bhhL, bdv, hrs);
    }
}

__global__ __launch_bounds__(NT, 2) void gru_persist(
    const float* __restrict__ x, const float* __restrict__ W_ih,
    const float* __restrict__ W_hh, const float* __restrict__ b_ih,
    const float* __restrict__ b_hh, const float* __restrict__ W_dec,
    const float* __restrict__ b_dec, char* __restrict__ wsb,
    float* __restrict__ out)
{
    __shared__ unsigned short Bst[16 * 9 * 512];   // 144KB fragment-linear W_hh
    __shared__ float xsA[32 * 28], xsB[32 * 28];   // 7KB x tiles (stride 28, col27 pad)
    __shared__ float P0[2 * 64 * 8], P1[2 * 64 * 8];  // 8KB exchange buffers
    __shared__ float bihL[NG], bhhL[NG];
    __shared__ int fastFlag;

    unsigned short* hpl = (unsigned short*)wsb;
    unsigned* cbase = (unsigned*)(wsb + WS_CNT);
    unsigned short* Dstg = (unsigned short*)(wsb + WS_DSTG);
    unsigned short* Wxg  = (unsigned short*)(wsb + WS_WXG);

    const int tid = threadIdx.x;
    const int bt  = blockIdx.x & 7;     // group == XCD if round-robin holds
    const int j   = blockIdx.x >> 3;    // 0..31
    const int b0A = bt * 64;
    const int b0B = bt * 64 + 32;
    const int g0  = j * 16;
    unsigned* cntA = cbase + bt * 16;         // 64B-strided counters
    unsigned* cntB = cbase + 128 + bt * 16;
    unsigned* pcnt = cbase + 256 + bt * 16;
    unsigned* flag = cbase + 384 + bt * 16;

    // ---- one-time: B-stream (triple-split W_hh, fragment-linear) ----
    for (int idx = tid; idx < 16 * 9 * 512; idx += NT) {
        int e = idx & 7, ln2 = (idx >> 3) & 63, s = idx >> 9;
        int p = s % 3, t = (s / 3) % 3, c = s / 9;
        int cc2 = ln2 & 15, qq2 = ln2 >> 4;
        int k = c * 32 + qq2 * 8 + e;
        int grow = t * Hsz + g0 + cc2;
        float v = W_hh[(size_t)grow * Hsz + k];
        unsigned short t1 = btrunc(v); float r1 = v - bup(t1);
        unsigned short t2 = btrunc(r1); float r2 = r1 - bup(t2);
        unsigned short t3 = btrunc(r2);
        Bst[idx] = (p == 0) ? t1 : (p == 1) ? t2 : t3;
    }
    if (tid < NG) {
        int grow = (tid >> 4) * Hsz + g0 + (tid & 15);
        bihL[tid] = b_ih[grow]; bhhL[tid] = b_hh[grow];
    }
    // x_0 staging, both chains
    {
        const int pxr = tid >> 4, pxc = (tid & 15) << 1;
        #pragma unroll
        for (int e = 0; e < 2; ++e) {
            int ci = pxc + e;
            if (ci < 28) {
                xsA[pxr * 28 + ci] = (ci < Vsz) ? x[(size_t)(b0A + pxr) * TV + ci] : 0.f;
                xsB[pxr * 28 + ci] = (ci < Vsz) ? x[(size_t)(b0B + pxr) * TV + ci] : 0.f;
            }
        }
    }
    // ---- XCD consensus: fast path iff whole group on one XCD ----
    if (tid == 0) {
        unsigned xcc;
        asm volatile("s_getreg_b32 %0, hwreg(20, 0, 32)" : "=s"(xcc));
        __hip_atomic_fetch_or(flag, 1u << (xcc & 31), __ATOMIC_RELAXED,
                              __HIP_MEMORY_SCOPE_AGENT);
        asm volatile("s_waitcnt vmcnt(0)" ::: "memory");
    }
    group_barrier(pcnt, JB);
    if (tid == 0) {
        unsigned f = __hip_atomic_load(flag, __ATOMIC_RELAXED, __HIP_MEMORY_SCOPE_AGENT);
        fastFlag = (__popc(f) == 1) ? 1 : 0;
    }
    __syncthreads();
    const bool fastv = (fastFlag != 0);

    const int cc = tid & 15;
    const int vcol = (j << 4) + cc;
    const float bdv = (j < 2 && vcol < Vsz) ? b_dec[vcol] : 0.f;
    __amdgpu_buffer_rsrc_t hrs = make_rsrc((void*)hpl, (unsigned)(2u * 3u * BH * 2u));

    if (fastv)
        run_chains<true>(b0A, b0B, g0, j, cntA, cntB, xsA, xsB, x, out,
                         Dstg, Wxg, Bst, P0, P1, bihL, bhhL, bdv, hrs);
    else
        run_chains<false>(b0A, b0B, g0, j, cntA, cntB, xsA, xsB, x, out,
                          Dstg, Wxg, Bst, P0, P1, bihL, bhhL, bdv, hrs);
}

extern "C" void kernel_launch(void* const* d_in, const int* in_sizes, int n_in,
                              void* d_out, int out_size, void* d_ws, size_t ws_size,
                              hipStream_t stream) {
    const float* x     = (const float*)d_in[0];
    const float* W_ih  = (const float*)d_in[1];
    const float* W_hh  = (const float*)d_in[2];
    const float* b_ih  = (const float*)d_in[3];
    const float* b_hh  = (const float*)d_in[4];
    const float* W_dec = (const float*)d_in[5];
    const float* b_dec = (const float*)d_in[6];
    float* out = (float*)d_out;
    char* wsb  = (char*)d_ws;

    init_ws_kernel<<<768, 256, 0, stream>>>(
        (unsigned short*)wsb, (unsigned*)(wsb + WS_CNT),
        (unsigned short*)(wsb + WS_DSTG), (unsigned short*)(wsb + WS_WXG),
        W_ih, W_dec);

    // Plain launch: ~159 KB LDS -> 1 block/CU, grid == 256 == CU count ->
    // all blocks co-resident; chain barriers cannot deadlock (R4-R12-proven).
    gru_persist<<<dim3(NBLK), dim3(NT), 0, stream>>>(
        x, W_ih, W_hh, b_ih, b_hh, W_dec, b_dec, wsb, out);
}

// Round 16
// 14586.964 us; speedup vs baseline: 1.2149x; 1.2149x over previous
//
#include <hip/hip_runtime.h>
#include <math.h>

#define Bsz 512
#define Tsz 1024
#define Vsz 27
#define Hsz 512
#define BH (Bsz * Hsz)
#define TV (Tsz * Vsz)
#define NBLK 256
#define NT 512
#define BT 64        // batch rows per group: 8 groups x 32 j-blocks
#define JB 32        // blocks per group
#define NG 48        // gate rows per block (16 r + 16 z + 16 n), HPc=16

typedef float f32x4 __attribute__((ext_vector_type(4)));
typedef short s16x8 __attribute__((ext_vector_type(8)));
typedef unsigned int u32x4 __attribute__((ext_vector_type(4)));
#define MFMA __builtin_amdgcn_mfma_f32_16x16x32_bf16

// ws byte offsets
#define WS_CNT  ((size_t)2 * 3 * BH * 2)             // consensus counters (4KB)
#define WS_FLG  (WS_CNT + 4096)                      // 32KB producer flags
#define WS_DSTG (WS_FLG + 32768)                     // 32KB decode stream
#define WS_WXG  (WS_DSTG + (size_t)2 * 16 * 512 * 2) // 192KB x-fold W stream

__device__ __forceinline__ unsigned short btrunc(float x) {   // bf16 RTZ bits
    return (unsigned short)(__float_as_uint(x) >> 16);
}
__device__ __forceinline__ float bup(unsigned short b) {
    return __uint_as_float(((unsigned)b) << 16);
}
__device__ __forceinline__ unsigned short brne(float x) {     // bf16 RNE bits
    unsigned u = __float_as_uint(x);
    return (unsigned short)((u + 0x7FFFu + ((u >> 16) & 1u)) >> 16);
}
__device__ __forceinline__ __amdgpu_buffer_rsrc_t make_rsrc(void* p, unsigned bytes) {
    return __builtin_amdgcn_make_buffer_rsrc(p, (short)0, (int)bytes, 0x00020000);
}
template<bool FAST>
__device__ __forceinline__ s16x8 loadA(__amdgpu_buffer_rsrc_t r, int off) {
    u32x4 d = __builtin_amdgcn_raw_buffer_load_b128(r, off, 0, FAST ? 0 : 0x11);
    return __builtin_bit_cast(s16x8, d);
}
template<bool FAST>
__device__ __forceinline__ void storeH(__amdgpu_buffer_rsrc_t r, int off, unsigned short v) {
    __builtin_amdgcn_raw_buffer_store_b16(v, r, off, 0, FAST ? 0 : 0x11);
}
// producer flags: PROVEN primitives only (__hip_atomic_*, agent scope, R4-R13)
__device__ __forceinline__ unsigned flag_get(unsigned* p) {
    return __hip_atomic_load(p, __ATOMIC_RELAXED, __HIP_MEMORY_SCOPE_AGENT);
}
__device__ __forceinline__ void gate_spin(unsigned* flags, int bt, int c, int step) {
    unsigned* fA = flags + (size_t)((bt << 5) + (c << 1)) * 32;
    unsigned* fB = fA + 32;
    while ((int)flag_get(fA) < step || (int)flag_get(fB) < step)
        __builtin_amdgcn_s_sleep(2);
}

// 6-product triple-split fp32-grade MFMA (R7-R12 proven)
#define PROD6(ACC, B1_, B2_, B3_, A1_, A2_, A3_) do { \
    ACC = MFMA(A1_, B1_, ACC, 0, 0, 0); \
    ACC = MFMA(A1_, B2_, ACC, 0, 0, 0); \
    ACC = MFMA(A2_, B1_, ACC, 0, 0, 0); \
    ACC = MFMA(A1_, B3_, ACC, 0, 0, 0); \
    ACC = MFMA(A2_, B2_, ACC, 0, 0, 0); \
    ACC = MFMA(A3_, B1_, ACC, 0, 0, 0); } while (0)
#define PROD5(ACC, B1_, B2_, A1_, A2_, A3_) do { \
    ACC = MFMA(A1_, B1_, ACC, 0, 0, 0); \
    ACC = MFMA(A1_, B2_, ACC, 0, 0, 0); \
    ACC = MFMA(A2_, B1_, ACC, 0, 0, 0); \
    ACC = MFMA(A2_, B2_, ACC, 0, 0, 0); \
    ACC = MFMA(A3_, B1_, ACC, 0, 0, 0); } while (0)

__global__ void init_ws_kernel(unsigned short* __restrict__ hpl, unsigned* __restrict__ cntr,
                               unsigned short* __restrict__ Dstg, unsigned short* __restrict__ Wxg,
                               const float* __restrict__ W_ih, const float* __restrict__ W_dec)
{
    size_t gid = (size_t)blockIdx.x * 256 + threadIdx.x;
    size_t gsz = (size_t)gridDim.x * 256;
    for (size_t i = gid; i < (size_t)(2 * 3 * BH * 2) / 16; i += gsz)
        ((uint4*)hpl)[i] = make_uint4(0u, 0u, 0u, 0u);
    // zero consensus counters + producer flags (4KB + 32KB = 9216 uints)
    for (size_t i = gid; i < 9216; i += gsz) cntr[i] = 0u;
    // decode stream [jj:2][c:16][lane:64][8]
    for (size_t i = gid; i < 2 * 16 * 512; i += gsz) {
        int e = i & 7, ln2 = (i >> 3) & 63, c = (i >> 9) & 15, jj = (int)(i >> 13);
        int cc2 = ln2 & 15, qq2 = ln2 >> 4;
        int k = c * 32 + qq2 * 8 + e;
        int vr = jj * 16 + cc2;
        Dstg[i] = (vr < Vsz) ? brne(W_dec[(size_t)vr * Hsz + k]) : (unsigned short)0;
    }
    // x-fold W stream [grow:1536][p:2][k:32]
    for (size_t i = gid; i < 1536 * 64; i += gsz) {
        int k = i & 31, p = (i >> 5) & 1, grow = (int)(i >> 6);
        float v = (k < Vsz) ? W_ih[grow * Vsz + k] : 0.f;
        unsigned short t1 = btrunc(v); float r1 = v - bup(t1);
        unsigned short t2 = btrunc(r1);
        Wxg[i] = p ? t2 : t1;
    }
}

// atomic group barrier — used ONCE for the XCD-consensus pre-barrier (proven)
__device__ __forceinline__ void group_barrier(unsigned* c, unsigned target) {
    __syncthreads();
    if (threadIdx.x == 0) {
        __hip_atomic_fetch_add(c, 1u, __ATOMIC_RELAXED, __HIP_MEMORY_SCOPE_AGENT);
        while (__hip_atomic_load(c, __ATOMIC_RELAXED, __HIP_MEMORY_SCOPE_AGENT) < target)
            __builtin_amdgcn_s_sleep(2);
    }
    __syncthreads();
}

template<bool FAST>
__device__ __forceinline__ void gru_loop(
    const float* __restrict__ x, float* __restrict__ out,
    const unsigned short* __restrict__ Dstg, const unsigned short* __restrict__ Wxg,
    unsigned* __restrict__ flags, __amdgpu_buffer_rsrc_t hrs,
    const unsigned short* Bst, float* xs, float* nscr,
    const float* bihL, const float* bhhL, float bdv,
    int tid, int bt, int j, int b0, int g0)
{
    const int w = tid >> 6, ln = tid & 63;
    const int m = w & 3, half = w >> 2;
    const int cc = ln & 15, qq = ln >> 4;
    const int rowA = (m << 4) + cc;
    const int xr = tid >> 3, xc = (tid & 7) << 2;
    const int vcol = (j << 4) + cc;
    const int rowBase = ((b0 + rowA) * Hsz + (qq << 3)) << 1;   // bytes
    unsigned* myflag = flags + (size_t)((bt << 5) + j) * 32;

    float hk[4] = {0.f, 0.f, 0.f, 0.f};

    for (int i = 0; i <= Tsz; ++i) {
        if (FAST) asm volatile("buffer_inv" ::: "memory");   // drop stale L1 lines
        // prefetch x_{i+1} to regs
        float xreg[4];
        if (i + 1 < Tsz) {
            #pragma unroll
            for (int e = 0; e < 4; ++e) {
                int ci = xc + e;
                xreg[e] = (ci < Vsz) ? x[(size_t)(b0 + xr) * TV + (size_t)(i + 1) * Vsz + ci] : 0.f;
            }
        }
        const int voffA0 = (i & 1) * (3 * BH * 2) + rowBase;

        f32x4 accR = {0,0,0,0}, accZ = {0,0,0,0}, accNi = {0,0,0,0};
        f32x4 accNh = {0,0,0,0}, accD = {0,0,0,0};

        // ---- producer-gated K-loop, IN ORDER 0..15 (summation order identical
        // to the passing R12 kernel; R15's rotated order is the single change
        // being reverted), 2-deep gate pipeline, 1-deep A pipeline ----
        gate_spin(flags, bt, 0, i);
        s16x8 A1c = loadA<FAST>(hrs, voffA0);
        s16x8 A2c = loadA<FAST>(hrs, voffA0 + BH * 2);
        s16x8 A3c = loadA<FAST>(hrs, voffA0 + 2 * BH * 2);
        unsigned fA1 = flag_get(flags + (size_t)((bt << 5) + 2) * 32);
        unsigned fB1 = flag_get(flags + (size_t)((bt << 5) + 3) * 32);
        #pragma unroll
        for (int c = 0; c < 16; ++c) {
            s16x8 A1n, A2n, A3n;
            if (c < 15) {
                const int cn = c + 1;
                if ((int)fA1 < i || (int)fB1 < i) gate_spin(flags, bt, cn, i);
                A1n = loadA<FAST>(hrs, voffA0 + cn * 64);
                A2n = loadA<FAST>(hrs, voffA0 + cn * 64 + BH * 2);
                A3n = loadA<FAST>(hrs, voffA0 + cn * 64 + 2 * BH * 2);
                if (c < 14) {
                    const int c2 = c + 2;
                    fA1 = flag_get(flags + (size_t)((bt << 5) + (c2 << 1)) * 32);
                    fB1 = flag_get(flags + (size_t)((bt << 5) + (c2 << 1) + 1) * 32);
                }
            }
            const unsigned short* bs = Bst + (size_t)(c * 9) * 512 + (ln << 3);
            if (half == 0) {
                s16x8 B1 = *(const s16x8*)(bs);
                s16x8 B2 = *(const s16x8*)(bs + 512);
                s16x8 B3 = *(const s16x8*)(bs + 1024);
                PROD6(accR, B1, B2, B3, A1c, A2c, A3c);
                s16x8 C1 = *(const s16x8*)(bs + 1536);
                s16x8 C2 = *(const s16x8*)(bs + 2048);
                s16x8 C3 = *(const s16x8*)(bs + 2560);
                PROD6(accZ, C1, C2, C3, A1c, A2c, A3c);
            } else {
                s16x8 N1 = *(const s16x8*)(bs + 3072);
                s16x8 N2 = *(const s16x8*)(bs + 3584);
                s16x8 N3 = *(const s16x8*)(bs + 4096);
                PROD6(accNh, N1, N2, N3, A1c, A2c, A3c);
                if (j < 2) {
                    s16x8 D1 = *(const s16x8*)(Dstg + (size_t)((j << 4) + c) * 512 + (ln << 3));
                    accD = MFMA(A1c, D1, accD, 0, 0, 0);
                    accD = MFMA(A2c, D1, accD, 0, 0, 0);
                }
            }
            A1c = A1n; A2c = A2n; A3c = A3n;
        }

        // x-fold (half0): triple-split x from LDS, 2-plane W from global stream
        if (half == 0 && i < Tsz) {
            s16x8 A1, A2, A3;
            #pragma unroll
            for (int e = 0; e < 8; ++e) {
                float v = xs[rowA * 32 + (qq << 3) + e];
                unsigned short s1 = btrunc(v); float r1 = v - bup(s1);
                unsigned short s2 = btrunc(r1); float r2 = r1 - bup(s2);
                unsigned short s3 = btrunc(r2);
                A1[e] = (short)s1; A2[e] = (short)s2; A3[e] = (short)s3;
            }
            {
                const unsigned short* wb = Wxg + (size_t)(g0 + cc) * 64 + (qq << 3);
                s16x8 B1 = *(const s16x8*)(wb);
                s16x8 B2 = *(const s16x8*)(wb + 32);
                PROD5(accR, B1, B2, A1, A2, A3);
            }
            {
                const unsigned short* wb = Wxg + (size_t)(Hsz + g0 + cc) * 64 + (qq << 3);
                s16x8 B1 = *(const s16x8*)(wb);
                s16x8 B2 = *(const s16x8*)(wb + 32);
                PROD5(accZ, B1, B2, A1, A2, A3);
            }
            {
                const unsigned short* wb = Wxg + (size_t)(2 * Hsz + g0 + cc) * 64 + (qq << 3);
                s16x8 B1 = *(const s16x8*)(wb);
                s16x8 B2 = *(const s16x8*)(wb + 32);
                PROD5(accNi, B1, B2, A1, A2, A3);
            }
        }

        __syncthreads();   // S2: xs reads done, half1 MFMAs done
        if (half == 1 && i < Tsz)
            *(f32x4*)&nscr[(size_t)(m * 64 + ln) * 4] = accNh;
        if (i + 1 < Tsz) {
            #pragma unroll
            for (int e = 0; e < 4; ++e) xs[xr * 32 + xc + e] = xreg[e];
        }
        __syncthreads();   // S3: nscr ready

        if (half == 0 && i < Tsz) {
            const int wpar = ((i + 1) & 1) * (3 * BH * 2);
            const float* nh4 = &nscr[(size_t)(m * 64 + ln) * 4];
            #pragma unroll
            for (int r = 0; r < 4; ++r) {
                float rv = accR[r] + bihL[cc] + bhhL[cc];
                float zv = accZ[r] + bihL[16 + cc] + bhhL[16 + cc];
                float ni = accNi[r] + bihL[32 + cc];
                float nh = nh4[r] + bhhL[32 + cc];
                float rg = 1.f / (1.f + expf(-rv));
                float zg = 1.f / (1.f + expf(-zv));
                float ng = tanhf(ni + rg * nh);
                float hv = (1.f - zg) * ng + zg * hk[r];
                hk[r] = hv;
                int e2 = wpar + (((b0 + (m << 4) + (qq << 2) + r) * Hsz + g0 + cc) << 1);
                unsigned short s1 = btrunc(hv); float r1 = hv - bup(s1);
                unsigned short s2 = btrunc(r1); float r2 = r1 - bup(s2);
                unsigned short s3 = btrunc(r2);
                storeH<FAST>(hrs, e2, s1);
                storeH<FAST>(hrs, e2 + BH * 2, s2);
                storeH<FAST>(hrs, e2 + 2 * BH * 2, s3);
            }
        }
        if (i < Tsz) {
            // publish: h_{i+1} stores AND h_i reads drained -> flag = i+1.
            asm volatile("s_waitcnt vmcnt(0)" ::: "memory");
            __syncthreads();
            if (tid == 0)
                __hip_atomic_store(myflag, (unsigned)(i + 1), __ATOMIC_RELAXED,
                                   __HIP_MEMORY_SCOPE_AGENT);
        }
        // logits[:, i-1, :] from h_i (after publish; overlaps next step)
        if (i > 0 && half == 1 && j < 2 && vcol < Vsz) {
            #pragma unroll
            for (int r = 0; r < 4; ++r) {
                size_t brow = (size_t)(b0 + (m << 4) + (qq << 2) + r);
                out[brow * TV + (size_t)(i - 1) * Vsz + vcol] = accD[r] + bdv;
            }
        }
    }
}

__global__ __launch_bounds__(NT, 2) void gru_persist(
    const float* __restrict__ x, const float* __restrict__ W_ih,
    const float* __restrict__ W_hh, const float* __restrict__ b_ih,
    const float* __restrict__ b_hh, const float* __restrict__ W_dec,
    const float* __restrict__ b_dec, char* __restrict__ wsb,
    float* __restrict__ out)
{
    __shared__ unsigned short Bst[16 * 9 * 512];   // [c][tile*plane][lane][8] 144KB
    __shared__ float xs[BT * 32];                  // 8KB
    __shared__ float nscr[4 * 64 * 4];             // 4KB n-gate exchange
    __shared__ float bihL[NG], bhhL[NG];
    __shared__ int fastFlag;

    unsigned short* hpl = (unsigned short*)wsb;
    unsigned* cbase = (unsigned*)(wsb + WS_CNT);
    unsigned* flags = (unsigned*)(wsb + WS_FLG);
    unsigned short* Dstg = (unsigned short*)(wsb + WS_DSTG);
    unsigned short* Wxg  = (unsigned short*)(wsb + WS_WXG);

    const int tid = threadIdx.x;
    const int bt  = blockIdx.x & 7;     // group == XCD if round-robin holds
    const int j   = blockIdx.x >> 3;    // 0..31
    const int b0  = bt * BT;
    const int g0  = j * 16;
    unsigned* pcnt  = cbase + 16 + bt;        // consensus barrier counter
    unsigned* xmask = cbase + 32 + bt;        // XCD-id mask

    // ---- one-time: B-stream (triple-split W_hh, fragment-linear) ----
    for (int idx = tid; idx < 16 * 9 * 512; idx += NT) {
        int e = idx & 7, ln2 = (idx >> 3) & 63, s = idx >> 9;
        int p = s % 3, t = (s / 3) % 3, c = s / 9;
        int cc2 = ln2 & 15, qq2 = ln2 >> 4;
        int k = c * 32 + qq2 * 8 + e;
        int grow = t * Hsz + g0 + cc2;
        float v = W_hh[(size_t)grow * Hsz + k];
        unsigned short t1 = btrunc(v); float r1 = v - bup(t1);
        unsigned short t2 = btrunc(r1); float r2 = r1 - bup(t2);
        unsigned short t3 = btrunc(r2);
        Bst[idx] = (p == 0) ? t1 : (p == 1) ? t2 : t3;
    }
    if (tid < NG) {
        int grow = (tid >> 4) * Hsz + g0 + (tid & 15);
        bihL[tid] = b_ih[grow]; bhhL[tid] = b_hh[grow];
    }
    // x_0 staging
    {
        int xr = tid >> 3, xc = (tid & 7) << 2;
        #pragma unroll
        for (int e = 0; e < 4; ++e) {
            int ci = xc + e;
            xs[xr * 32 + ci] = (ci < Vsz) ? x[(size_t)(b0 + xr) * TV + ci] : 0.f;
        }
    }
    // ---- XCD consensus: fast path iff whole group on one XCD ----
    if (tid == 0) {
        unsigned xcc;
        asm volatile("s_getreg_b32 %0, hwreg(20, 0, 32)" : "=s"(xcc));
        __hip_atomic_fetch_or(xmask, 1u << (xcc & 31), __ATOMIC_RELAXED,
                              __HIP_MEMORY_SCOPE_AGENT);
        asm volatile("s_waitcnt vmcnt(0)" ::: "memory");
    }
    group_barrier(pcnt, JB);
    if (tid == 0) {
        unsigned f = __hip_atomic_load(xmask, __ATOMIC_RELAXED, __HIP_MEMORY_SCOPE_AGENT);
        fastFlag = (__popc(f) == 1) ? 1 : 0;
    }
    __syncthreads();
    const bool fastv = (fastFlag != 0);

    const int cc = tid & 15;
    const int vcol = (j << 4) + cc;
    const float bdv = (j < 2 && vcol < Vsz) ? b_dec[vcol] : 0.f;
    __amdgpu_buffer_rsrc_t hrs = make_rsrc((void*)hpl, (unsigned)(2u * 3u * BH * 2u));

    if (fastv)
        gru_loop<true>(x, out, Dstg, Wxg, flags, hrs, Bst, xs, nscr, bihL, bhhL, bdv,
                       tid, bt, j, b0, g0);
    else
        gru_loop<false>(x, out, Dstg, Wxg, flags, hrs, Bst, xs, nscr, bihL, bhhL, bdv,
                        tid, bt, j, b0, g0);
}

extern "C" void kernel_launch(void* const* d_in, const int* in_sizes, int n_in,
                              void* d_out, int out_size, void* d_ws, size_t ws_size,
                              hipStream_t stream) {
    const float* x     = (const float*)d_in[0];
    const float* W_ih  = (const float*)d_in[1];
    const float* W_hh  = (const float*)d_in[2];
    const float* b_ih  = (const float*)d_in[3];
    const float* b_hh  = (const float*)d_in[4];
    const float* W_dec = (const float*)d_in[5];
    const float* b_dec = (const float*)d_in[6];
    float* out = (float*)d_out;
    char* wsb  = (char*)d_ws;

    init_ws_kernel<<<768, 256, 0, stream>>>(
        (unsigned short*)wsb, (unsigned*)(wsb + WS_CNT),
        (unsigned short*)(wsb + WS_DSTG), (unsigned short*)(wsb + WS_WXG),
        W_ih, W_dec);

    // Plain launch: ~157 KB LDS -> 1 block/CU, grid == 256 == CU count ->
    // all blocks co-resident. Producer-flag dataflow cannot deadlock:
    // flags are monotonic, every block publishes after every step
    // (induction: step-i gates need only step-(i-1) publishes).
    gru_persist<<<dim3(NBLK), dim3(NT), 0, stream>>>(
        x, W_ih, W_hh, b_ih, b_hh, W_dec, b_dec, wsb, out);
}